// Round 7
// baseline (233.122 us; speedup 1.0000x reference)
//
#include <hip/hip_runtime.h>

// Self-attention block (non-local): B=8, C=256, H=W=64 -> N=4096, dk=64.
// out = x + gamma * softmax((Wq x)^T (Wk x) / 8) applied to (Wv x).
// Pipeline: prep (weights->bf16, fold log2e/8 into Wq) -> proj (MFMA GEMM,
// in-LDS transpose of x) -> flash (shared-P attention, m-block 64, kv-block
// 128).  R7: V goes L2 -> registers (per-wave-exclusive channel slice, no
// sharing, no LDS round trip); all 16 V-frag loads issue at the TOP of
// region A and are fenced by the barrier (cannot sink).  P is bf16 in
// double-buffered swizzled LDS (16-slot XOR), ONE barrier per iter.
// K(t+1) prefetched under region B's MFMAs.  Max-free softmax.

typedef __attribute__((ext_vector_type(8)))  short short8;
typedef __attribute__((ext_vector_type(4)))  short short4v;
typedef __attribute__((ext_vector_type(16))) float f32x16;
typedef __attribute__((ext_vector_type(4)))  float f32x4;

#define B_   8
#define C_   256
#define N_   4096
#define DK_  64
// log2(e) / sqrt(dk) = 1.4426950408889634 / 8
#define QSCL 0.18033688011112043f

#if defined(__has_builtin)
#if __has_builtin(__builtin_amdgcn_exp2f)
#define EXP2F(x) __builtin_amdgcn_exp2f(x)
#else
#define EXP2F(x) exp2f(x)
#endif
#else
#define EXP2F(x) exp2f(x)
#endif

// float -> bf16 bits, round-to-nearest-even (inputs are finite; no NaN path)
__device__ __forceinline__ unsigned short bfb(float f) {
  unsigned u = __builtin_bit_cast(unsigned, f);
  unsigned r = (u + 0x7fffu + ((u >> 16) & 1u)) >> 16;
  return (unsigned short)r;
}

// packed f32x2 -> bf16x2 (low = a, high = b), RNE
__device__ __forceinline__ unsigned cvtpk(float a, float b) {
  unsigned r;
  asm("v_cvt_pk_bf16_f32 %0, %1, %2" : "=v"(r) : "v"(a), "v"(b));
  return r;
}

// ---------------------------------------------------------------------------
// Kernel 1: weight prep.  W'[384][256] bf16 = [Wq*QSCL ; Wk ; Wv], bias'[384].
// ---------------------------------------------------------------------------
__global__ void prep_kernel(const float* __restrict__ Wq, const float* __restrict__ bq,
                            const float* __restrict__ Wk, const float* __restrict__ bk,
                            const float* __restrict__ Wv, const float* __restrict__ bv,
                            unsigned short* __restrict__ Wc, float* __restrict__ biasc) {
  int idx = blockIdx.x * 256 + threadIdx.x;
  if (idx < 384 * 256) {
    int ch = idx >> 8, c = idx & 255;
    float v;
    if (ch < 64)       v = Wq[ch * 256 + c] * QSCL;
    else if (ch < 128) v = Wk[(ch - 64) * 256 + c];
    else               v = Wv[(ch - 128) * 256 + c];
    Wc[idx] = bfb(v);
  }
  if (idx < 384) {
    float bb;
    if (idx < 64)       bb = bq[idx] * QSCL;
    else if (idx < 128) bb = bk[idx - 64];
    else                bb = bv[idx - 128];
    biasc[idx] = bb;
  }
}

// ---------------------------------------------------------------------------
// Kernel 2: projections.  Per (batch, 64-row n-block): stage x[256c][64n]
// transposed into LDS as bf16 (XOR-swizzled), then OUT[n][ch] = Xt * W'^T via
// 32x32x16 bf16 MFMA.  Outputs: Qt,Kt [B][N][64] (n-major), V [B][C][N].
// ---------------------------------------------------------------------------
__global__ __launch_bounds__(256, 2) void proj_kernel(
    const float* __restrict__ x, const unsigned short* __restrict__ Wc,
    const float* __restrict__ biasc, unsigned short* __restrict__ Qt,
    unsigned short* __restrict__ Kt, unsigned short* __restrict__ V) {
  __shared__ unsigned short XT[64 * 256];  // [n][c] bf16, swizzled, 32 KiB
  const int tid = threadIdx.x;
  const int b = blockIdx.y;
  const int n0 = blockIdx.x * 64;

  // stage: x[b][c][n0+0..63] fp32 -> XT[n][c] bf16 (transpose), swizzle:
  // ushort idx = n*256 + (((c>>3) ^ (n&15))<<3) + (c&7)
  {
    const f32x4* x4 = (const f32x4*)(x + ((size_t)b * C_) * N_ + n0);
    int c = tid >> 4;                  // 0..15 (+16 per pass)
    const int nl = (tid & 15) << 2;    // 0,4,...,60
#pragma unroll
    for (int p = 0; p < 16; ++p, c += 16) {
      f32x4 v = x4[(size_t)c * (N_ / 4) + (nl >> 2)];
#pragma unroll
      for (int i = 0; i < 4; ++i) {
        int n = nl + i;
        XT[n * 256 + ((((c >> 3) ^ (n & 15)) << 3) | (c & 7))] = bfb(v[i]);
      }
    }
  }
  __syncthreads();

  const int lane = tid & 63, li = lane & 31, hi = lane >> 5;
  const int w = tid >> 6;
  const int ch0 = 96 * w;  // this wave's 96 output channels (3 x 32)

  f32x16 acc[2][3];
#pragma unroll
  for (int mt = 0; mt < 2; ++mt)
#pragma unroll
    for (int j = 0; j < 3; ++j)
#pragma unroll
      for (int r = 0; r < 16; ++r) acc[mt][j][r] = 0.f;

  const short8* Wc8 = (const short8*)Wc;
#pragma unroll
  for (int ks = 0; ks < 16; ++ks) {
    // A-frags: lane holds Xt[n=32*mt+li][c=16*ks+8*hi .. +8]
    int chunk = 2 * ks + hi;
    short8 a0 = *(const short8*)&XT[(li) * 256 + ((chunk ^ (li & 15)) << 3)];
    short8 a1 = *(const short8*)&XT[(32 + li) * 256 + ((chunk ^ (li & 15)) << 3)];
#pragma unroll
    for (int j = 0; j < 3; ++j) {
      short8 bf = Wc8[(size_t)(ch0 + 32 * j + li) * 32 + chunk];
      acc[0][j] = __builtin_amdgcn_mfma_f32_32x32x16_bf16(a0, bf, acc[0][j], 0, 0, 0);
      acc[1][j] = __builtin_amdgcn_mfma_f32_32x32x16_bf16(a1, bf, acc[1][j], 0, 0, 0);
    }
  }

  // epilogue: D[row=n][col=ch], row = (r&3)+8*(r>>2)+4*hi + 32*mt, col = li
#pragma unroll
  for (int j = 0; j < 3; ++j) {
    const int chb = ch0 + 32 * j;  // wave-uniform 32-block, never straddles Q/K/V
    const int ch = chb + li;
    const float bias = biasc[ch];
#pragma unroll
    for (int mt = 0; mt < 2; ++mt) {
      if (chb < 64) {
#pragma unroll
        for (int r = 0; r < 16; ++r) {
          int n = n0 + 32 * mt + (r & 3) + 8 * (r >> 2) + 4 * hi;
          Qt[((size_t)(b * N_ + n) << 6) + ch] = bfb(acc[mt][j][r] + bias);
        }
      } else if (chb < 128) {
#pragma unroll
        for (int r = 0; r < 16; ++r) {
          int n = n0 + 32 * mt + (r & 3) + 8 * (r >> 2) + 4 * hi;
          Kt[((size_t)(b * N_ + n) << 6) + (ch - 64)] = bfb(acc[mt][j][r] + bias);
        }
      } else {
        const int cv = ch - 128;
#pragma unroll
        for (int q = 0; q < 4; ++q) {  // 4 consecutive n per 8B store
          short4v pk;
#pragma unroll
          for (int i = 0; i < 4; ++i) pk[i] = (short)bfb(acc[mt][j][4 * q + i] + bias);
          int n = n0 + 32 * mt + 8 * q + 4 * hi;
          *(short4v*)&V[(size_t)(b * C_ + cv) * N_ + n] = pk;
        }
      }
    }
  }
}

// ---------------------------------------------------------------------------
// Kernel 3: attention.  Grid 512 x 256 threads (4 waves).
// b = id & 7 (batch <-> XCD), m0 = (id >> 3) * 64.  kv-block 128.
// Region A(t): issue ALL 16 V-frag loads for t (L2->reg, fenced by barrier);
// compute S for this wave's 32-kv slice x 64 m (32x32 MFMA, K preloaded);
// exp2 + pack P bf16 into swizzled LDS buffer t&1.  __syncthreads.
// Region B(t): prefetch K(t+1); PV with 16x16x32 MFMA, P A-frags from LDS,
// V B-frags from regs.  No second barrier (P double-buffered; bar(t+1)
// orders B(t) reads before A(t+2) overwrites).
// P byte addr: buf*32768 + m*256 + (kvbyte ^ ((m&15)<<4)).
// ---------------------------------------------------------------------------
__global__ __launch_bounds__(256, 2) void flash_kernel(
    const unsigned short* __restrict__ Qt, const unsigned short* __restrict__ Kt,
    const unsigned short* __restrict__ V, const float* __restrict__ x,
    const float* __restrict__ gamma, float* __restrict__ out) {
  __shared__ unsigned short P[2][64 * 128];  // 2 x 16 KiB, swizzled
  __shared__ float den_lds[4][2][32];

  const int tid = threadIdx.x;
  const int lane = tid & 63, li = lane & 31, hi = lane >> 5;
  const int lg = lane >> 4, lc = lane & 15;   // 16-lane group / in-group id
  const int w = tid >> 6;
  const int id = blockIdx.x;
  const int b = id & 7;                // batch == XCD (round-robin dispatch)
  const int m0 = (id >> 3) << 6;       // 64-row m-block

  const short8* Qt8 = (const short8*)Qt;
  const short8* Kt8 = (const short8*)Kt;

  // Q B-frags (32x32 QK): lane holds Qt[m0+32*mt+li][16*ks+8*hi .. +8]
  short8 qb[2][4];
#pragma unroll
  for (int mt = 0; mt < 2; ++mt)
#pragma unroll
    for (int ks = 0; ks < 4; ++ks)
      qb[mt][ks] = Qt8[((size_t)b * N_ + m0 + 32 * mt + li) * 8 + 2 * ks + hi];

  f32x4 acc16[4][4];  // [t16 m-subtile][ct c-subtile]
#pragma unroll
  for (int t16 = 0; t16 < 4; ++t16)
#pragma unroll
    for (int ct = 0; ct < 4; ++ct)
#pragma unroll
      for (int r = 0; r < 4; ++r) acc16[t16][ct][r] = 0.f;
  float den[2] = {0.f, 0.f};

  // K rows for this wave's 32-kv slice: kv = kv0 + 32*w + li
  const size_t krow = (size_t)b * N_ + 32 * w + li;
  // V row pointers for the 4 c-subtiles: c = 64w + 16ct + lc, elem kv0+32ks+8lg
  const unsigned short* vrp[4];
#pragma unroll
  for (int ct = 0; ct < 4; ++ct)
    vrp[ct] = V + ((size_t)b * C_ + 64 * w + 16 * ct + lc) * N_ + 8 * lg;
  // P-read constants: t16 tile -> row m = 16*t16+lc, key = (m&15)<<4 = lc<<4
  const int pkey = lc << 4;

  // K(0) preload
  short8 kf[4];
#pragma unroll
  for (int ks = 0; ks < 4; ++ks)
    kf[ks] = Kt8[(krow + 0) * 8 + 2 * ks + hi];

#pragma unroll 2
  for (int t = 0; t < 32; ++t) {
    const int kv0 = t << 7;
    char* Pb = (char*)P[t & 1];

    // ---- region A: V loads first (fenced below + by the barrier) ----
    short8 vf[4][4];  // [ks][ct] this iter's V frags, live across the barrier
#pragma unroll
    for (int ks = 0; ks < 4; ++ks)
#pragma unroll
      for (int ct = 0; ct < 4; ++ct)
        vf[ks][ct] = *(const short8*)(vrp[ct] + kv0 + 32 * ks);
    asm volatile("" ::: "memory");  // loads may not sink below this point

    // ---- S for kv-slice [kv0+32w, +32), 64 m-rows (32x32 MFMA) ----
#pragma unroll
    for (int mt = 0; mt < 2; ++mt) {
      f32x16 st;
#pragma unroll
      for (int r = 0; r < 16; ++r) st[r] = 0.f;
#pragma unroll
      for (int ks = 0; ks < 4; ++ks)
        st = __builtin_amdgcn_mfma_f32_32x32x16_bf16(kf[ks], qb[mt][ks], st, 0, 0, 0);
      // S^T tile: lane holds m = 32*mt + li, n_local = (r&3)+8*(r>>2)+4*hi
      float e[16];
      float ds = 0.f;
#pragma unroll
      for (int r = 0; r < 16; ++r) {
        e[r] = EXP2F(st[r]);
        ds += e[r];
      }
      den[mt] += ds;
      // e[4u..4u+3]: kv_local = 32w+8u+4hi+{0..3} -> one 8B write at
      // kvbyte = 64w+16u+8hi, row m = 32mt+li, swizzle ^((m&15)<<4)
      char* rp = Pb + (32 * mt + li) * 256;
      const int key = (li & 15) << 4;
#pragma unroll
      for (int u = 0; u < 4; ++u) {
        unsigned lo = cvtpk(e[4 * u], e[4 * u + 1]);
        unsigned hh = cvtpk(e[4 * u + 2], e[4 * u + 3]);
        unsigned long long vv = (unsigned long long)lo | ((unsigned long long)hh << 32);
        *(unsigned long long*)(rp + ((64 * w + 16 * u + 8 * hi) ^ key)) = vv;
      }
    }

    __syncthreads();  // P[t&1] complete; V regs ride across

    // ---- region B: K(t+1) prefetch under PV ----
    if (t < 31) {
#pragma unroll
      for (int ks = 0; ks < 4; ++ks)
        kf[ks] = Kt8[(krow + kv0 + 128) * 8 + 2 * ks + hi];
    }

#pragma unroll
    for (int ks = 0; ks < 4; ++ks) {
      const int kb = 64 * ks + 16 * lg;
      short8 pf[4];
#pragma unroll
      for (int t16 = 0; t16 < 4; ++t16)
        pf[t16] = *(const short8*)(Pb + (16 * t16 + lc) * 256 + (kb ^ pkey));
      __builtin_amdgcn_s_setprio(1);
#pragma unroll
      for (int ct = 0; ct < 4; ++ct)
#pragma unroll
        for (int t16 = 0; t16 < 4; ++t16)
          acc16[t16][ct] = __builtin_amdgcn_mfma_f32_16x16x32_bf16(
              pf[t16], vf[ks][ct], acc16[t16][ct], 0, 0, 0);
      __builtin_amdgcn_s_setprio(0);
    }
    // no barrier: P double-buffered; bar(t+1) orders B(t) before A(t+2)
  }

  // ---- den reduction across waves ----
#pragma unroll
  for (int mt = 0; mt < 2; ++mt) {
    float dh = den[mt] + __shfl_xor(den[mt], 32);  // full m-row over wave's kv
    if (hi == 0) den_lds[w][mt][li] = dh;
  }
  __syncthreads();

  const float g = gamma[0];
  float ig0, ig1;
  {
    float d0 = den_lds[0][0][li] + den_lds[1][0][li] + den_lds[2][0][li] + den_lds[3][0][li];
    float d1 = den_lds[0][1][li] + den_lds[1][1][li] + den_lds[2][1][li] + den_lds[3][1][li];
    ig0 = g / d0;  // lane li: gamma/den for m-row m0+li
    ig1 = g / d1;  // m-row m0+32+li
  }

  // ---- epilogue: D row = 4*lg + r (consecutive m), col c = 16*ct + lc ----
#pragma unroll
  for (int t16 = 0; t16 < 4; ++t16) {
    f32x4 idn;
#pragma unroll
    for (int r = 0; r < 4; ++r)
      idn[r] = __shfl(t16 < 2 ? ig0 : ig1, 16 * (t16 & 1) + 4 * lg + r);
#pragma unroll
    for (int ct = 0; ct < 4; ++ct) {
      size_t off = ((size_t)b * C_ + 64 * w + 16 * ct + lc) * N_ + m0 + 16 * t16 + 4 * lg;
      f32x4 xv = *(const f32x4*)(x + off);
      f32x4 o;
#pragma unroll
      for (int r = 0; r < 4; ++r) o[r] = xv[r] + idn[r] * acc16[t16][ct][r];
      *(f32x4*)(out + off) = o;
    }
  }
}

// ---------------------------------------------------------------------------
extern "C" void kernel_launch(void* const* d_in, const int* in_sizes, int n_in,
                              void* d_out, int out_size, void* d_ws, size_t ws_size,
                              hipStream_t stream) {
  const float* x = (const float*)d_in[0];
  const float* Wq = (const float*)d_in[1];
  const float* bq = (const float*)d_in[2];
  const float* Wk = (const float*)d_in[3];
  const float* bk = (const float*)d_in[4];
  const float* Wv = (const float*)d_in[5];
  const float* bv = (const float*)d_in[6];
  const float* gamma = (const float*)d_in[7];
  float* out = (float*)d_out;

  char* ws = (char*)d_ws;
  unsigned short* Wc = (unsigned short*)(ws);                    // 196608 B
  float* biasc = (float*)(ws + 196608);                          // 1536 B
  unsigned short* Qt = (unsigned short*)(ws + 198144);           // 4 MiB
  unsigned short* Kt = (unsigned short*)(ws + 198144 + 4194304); // 4 MiB
  unsigned short* Vv = (unsigned short*)(ws + 198144 + 8388608); // 16 MiB
  // total ws use: ~25.4 MB

  prep_kernel<<<384, 256, 0, stream>>>(Wq, bq, Wk, bk, Wv, bv, Wc, biasc);
  proj_kernel<<<dim3(64, 8), 256, 0, stream>>>(x, Wc, biasc, Qt, Kt, Vv);
  flash_kernel<<<512, 256, 0, stream>>>(Qt, Kt, Vv, x, gamma, out);
}